// Round 1
// baseline (442.446 us; speedup 1.0000x reference)
//
#include <hip/hip_runtime.h>

typedef float floatx4 __attribute__((ext_vector_type(4)));
typedef __bf16 bf16x8 __attribute__((ext_vector_type(8)));

#define MFMA16x16x32 __builtin_amdgcn_mfma_f32_16x16x32_bf16

static __device__ __forceinline__ unsigned short f2bf(float f) {
  union { float f; unsigned int u; } v; v.f = f;
  unsigned int r = v.u + 0x7fffu + ((v.u >> 16) & 1u);
  return (unsigned short)(r >> 16);
}

// ---------------- cast fp32 -> bf16, vectorized x4 ----------------
__global__ void cast_kernel(const float* __restrict__ in,
                            unsigned short* __restrict__ out, int n4) {
  int i = blockIdx.x * blockDim.x + threadIdx.x;
  if (i < n4) {
    float4 v = ((const float4*)in)[i];
    ushort4 o;
    o.x = f2bf(v.x); o.y = f2bf(v.y); o.z = f2bf(v.z); o.w = f2bf(v.w);
    ((ushort4*)out)[i] = o;
  }
}

// ---------------- GEMM1: QKV = Xb @ Wqkvb + bqkv, scatter to Q/K/Vt ----------
// Xb: [4096][1024] bf16, Wb: [1024][3072] bf16 row-major.
// Q,K: [B*H=32][T=2048][64] bf16.  Vt: [32][64][2048] bf16.
// Tile 64x64, BK=32, 4 waves; wave w owns rows 16w..16w+15, 4 col subtiles.
__global__ __launch_bounds__(256) void gemm_qkv(
    const unsigned short* __restrict__ Xb,
    const unsigned short* __restrict__ Wb,
    const float* __restrict__ bias,
    unsigned short* __restrict__ Q,
    unsigned short* __restrict__ Kc,
    unsigned short* __restrict__ Vt) {
  const int Kd = 1024, N = 3072;
  const int n0 = blockIdx.x * 64;
  const int m0 = blockIdx.y * 64;
  const int tid = threadIdx.x;
  const int wave = tid >> 6, lane = tid & 63;
  const int l16 = lane & 15, lq = lane >> 4;

  __shared__ unsigned short As[64][32];   // [m][k]
  __shared__ unsigned short BsT[64][32];  // [n][k] (transposed in staging)

  floatx4 acc[4] = {{0.f,0.f,0.f,0.f},{0.f,0.f,0.f,0.f},
                    {0.f,0.f,0.f,0.f},{0.f,0.f,0.f,0.f}};

  const int arow = tid >> 2, acol = (tid & 3) * 8;
  const int brow = tid >> 3, bcol = (tid & 7) * 8;

  for (int k0 = 0; k0 < Kd; k0 += 32) {
    *(uint4*)(&As[arow][acol]) =
        *(const uint4*)(Xb + (size_t)(m0 + arow) * Kd + k0 + acol);
    unsigned short tmp[8];
    *(uint4*)tmp = *(const uint4*)(Wb + (size_t)(k0 + brow) * N + n0 + bcol);
#pragma unroll
    for (int j = 0; j < 8; ++j) BsT[bcol + j][brow] = tmp[j];
    __syncthreads();
    bf16x8 a = *(const bf16x8*)(&As[wave * 16 + l16][lq * 8]);
#pragma unroll
    for (int c = 0; c < 4; ++c) {
      bf16x8 b = *(const bf16x8*)(&BsT[c * 16 + l16][lq * 8]);
      acc[c] = MFMA16x16x32(a, b, acc[c], 0, 0, 0);
    }
    __syncthreads();
  }

  // whole block shares one (which, head) since n-tile spans 64 cols
  const int which = n0 >> 10;
  const int h = (n0 & 1023) >> 6;
#pragma unroll
  for (int c = 0; c < 4; ++c) {
    int col = n0 + c * 16 + l16;
    int dd = col & 63;
    float bv = bias[col];
#pragma unroll
    for (int r = 0; r < 4; ++r) {
      int row = m0 + wave * 16 + lq * 4 + r;  // global token row
      int bb = row >> 11, tt = row & 2047;
      unsigned short o = f2bf(acc[c][r] + bv);
      size_t bh = (size_t)(bb * 16 + h);
      if (which == 0)      Q [(bh * 2048 + tt) * 64 + dd] = o;
      else if (which == 1) Kc[(bh * 2048 + tt) * 64 + dd] = o;
      else                 Vt[(bh * 64 + dd) * 2048 + tt] = o;
    }
  }
}

// ---------------- flash attention: one (b,h) x 64 q-rows per block ----------
// scale = 0.5 (reference uses 1/sqrt(d//h) = 1/sqrt(4))
__global__ __launch_bounds__(256) void attn_kernel(
    const unsigned short* __restrict__ Q,
    const unsigned short* __restrict__ Kc,
    const unsigned short* __restrict__ Vt,
    unsigned short* __restrict__ AO) {
  const int T = 2048, D = 64;
  const int bh = blockIdx.y;        // 0..31
  const int q0 = blockIdx.x * 64;
  const int tid = threadIdx.x;
  const int wave = tid >> 6, lane = tid & 63;
  const int l16 = lane & 15, lq = lane >> 4;

  __shared__ unsigned short Ks[32][64];     // [k_local][d]
  __shared__ unsigned short Vs[64][32];     // [d][k_local]
  __shared__ unsigned short Ps[4][16][32];  // per-wave P: [q_local][k_local]

  // preload Q fragments (wave's 16 q rows, d split 0..31 / 32..63)
  const unsigned short* qb =
      Q + ((size_t)bh * T + q0 + wave * 16 + l16) * D;
  bf16x8 qf0 = *(const bf16x8*)(qb + lq * 8);
  bf16x8 qf1 = *(const bf16x8*)(qb + 32 + lq * 8);

  float m_run[4], l_run[4];
  floatx4 o_acc[4] = {{0.f,0.f,0.f,0.f},{0.f,0.f,0.f,0.f},
                      {0.f,0.f,0.f,0.f},{0.f,0.f,0.f,0.f}};
#pragma unroll
  for (int r = 0; r < 4; ++r) { m_run[r] = -1e30f; l_run[r] = 0.f; }

  const int krow = tid >> 3, kcol = (tid & 7) * 8;
  const int vd = tid >> 2, vtl = (tid & 3) * 8;

  for (int kt = 0; kt < T; kt += 32) {
    *(uint4*)(&Ks[krow][kcol]) =
        *(const uint4*)(Kc + ((size_t)bh * T + kt + krow) * D + kcol);
    *(uint4*)(&Vs[vd][vtl]) =
        *(const uint4*)(Vt + ((size_t)bh * D + vd) * T + kt + vtl);
    __syncthreads();

    // S tiles: 16 q x 32 k  (two 16-col MFMAs, K-dim = d = 64 in 2 chunks)
    floatx4 s[2];
#pragma unroll
    for (int ct = 0; ct < 2; ++ct) {
      bf16x8 kf0 = *(const bf16x8*)(&Ks[ct * 16 + l16][lq * 8]);
      bf16x8 kf1 = *(const bf16x8*)(&Ks[ct * 16 + l16][32 + lq * 8]);
      floatx4 z = {0.f, 0.f, 0.f, 0.f};
      z = MFMA16x16x32(qf0, kf0, z, 0, 0, 0);
      z = MFMA16x16x32(qf1, kf1, z, 0, 0, 0);
      s[ct] = z;
    }

    float al[4];
#pragma unroll
    for (int r = 0; r < 4; ++r) {
      float s0 = s[0][r] * 0.5f, s1 = s[1][r] * 0.5f;
      float m = fmaxf(s0, s1);
#pragma unroll
      for (int xm = 1; xm < 16; xm <<= 1) m = fmaxf(m, __shfl_xor(m, xm, 64));
      float mn = fmaxf(m_run[r], m);
      al[r] = __expf(m_run[r] - mn);
      m_run[r] = mn;
      float p0 = __expf(s0 - mn);
      float p1 = __expf(s1 - mn);
      float rs = p0 + p1;
#pragma unroll
      for (int xm = 1; xm < 16; xm <<= 1) rs += __shfl_xor(rs, xm, 64);
      l_run[r] = l_run[r] * al[r] + rs;
      Ps[wave][lq * 4 + r][l16] = f2bf(p0);
      Ps[wave][lq * 4 + r][16 + l16] = f2bf(p1);
#pragma unroll
      for (int c = 0; c < 4; ++c) o_acc[c][r] *= al[r];
    }
    __syncthreads();  // make Ps visible (and order vs next staging)

    bf16x8 pf = *(const bf16x8*)(&Ps[wave][l16][lq * 8]);
#pragma unroll
    for (int c = 0; c < 4; ++c) {
      bf16x8 vf = *(const bf16x8*)(&Vs[c * 16 + l16][lq * 8]);
      o_acc[c] = MFMA16x16x32(pf, vf, o_acc[c], 0, 0, 0);
    }
    __syncthreads();
  }

  // epilogue: AO[b][t][h*64+d] bf16
  const int b = bh >> 4, h = bh & 15;
#pragma unroll
  for (int c = 0; c < 4; ++c) {
#pragma unroll
    for (int r = 0; r < 4; ++r) {
      int t = q0 + wave * 16 + lq * 4 + r;
      int col = h * 64 + c * 16 + l16;
      float o = o_acc[c][r] / l_run[r];
      AO[((size_t)b * 2048 + t) * 1024 + col] = f2bf(o);
    }
  }
}

// ---------------- GEMM2: out = AO @ Wprojb + bproj (fp32 out) ----------------
__global__ __launch_bounds__(256) void gemm_proj(
    const unsigned short* __restrict__ Ab,
    const unsigned short* __restrict__ Wb,
    const float* __restrict__ bias,
    float* __restrict__ out) {
  const int Kd = 1024, N = 1024;
  const int n0 = blockIdx.x * 64;
  const int m0 = blockIdx.y * 64;
  const int tid = threadIdx.x;
  const int wave = tid >> 6, lane = tid & 63;
  const int l16 = lane & 15, lq = lane >> 4;

  __shared__ unsigned short As[64][32];
  __shared__ unsigned short BsT[64][32];

  floatx4 acc[4] = {{0.f,0.f,0.f,0.f},{0.f,0.f,0.f,0.f},
                    {0.f,0.f,0.f,0.f},{0.f,0.f,0.f,0.f}};

  const int arow = tid >> 2, acol = (tid & 3) * 8;
  const int brow = tid >> 3, bcol = (tid & 7) * 8;

  for (int k0 = 0; k0 < Kd; k0 += 32) {
    *(uint4*)(&As[arow][acol]) =
        *(const uint4*)(Ab + (size_t)(m0 + arow) * Kd + k0 + acol);
    unsigned short tmp[8];
    *(uint4*)tmp = *(const uint4*)(Wb + (size_t)(k0 + brow) * N + n0 + bcol);
#pragma unroll
    for (int j = 0; j < 8; ++j) BsT[bcol + j][brow] = tmp[j];
    __syncthreads();
    bf16x8 a = *(const bf16x8*)(&As[wave * 16 + l16][lq * 8]);
#pragma unroll
    for (int c = 0; c < 4; ++c) {
      bf16x8 b = *(const bf16x8*)(&BsT[c * 16 + l16][lq * 8]);
      acc[c] = MFMA16x16x32(a, b, acc[c], 0, 0, 0);
    }
    __syncthreads();
  }

#pragma unroll
  for (int c = 0; c < 4; ++c) {
    int col = n0 + c * 16 + l16;
    float bv = bias[col];
#pragma unroll
    for (int r = 0; r < 4; ++r) {
      int row = m0 + wave * 16 + lq * 4 + r;
      out[(size_t)row * N + col] = acc[c][r] + bv;
    }
  }
}

extern "C" void kernel_launch(void* const* d_in, const int* in_sizes, int n_in,
                              void* d_out, int out_size, void* d_ws,
                              size_t ws_size, hipStream_t stream) {
  const float* x     = (const float*)d_in[0];
  const float* Wqkv  = (const float*)d_in[1];
  const float* bqkv  = (const float*)d_in[2];
  const float* Wproj = (const float*)d_in[3];
  const float* bproj = (const float*)d_in[4];
  float* out = (float*)d_out;

  // workspace layout (bf16 elements), total 48 MiB
  unsigned short* Xb     = (unsigned short*)d_ws;  // 4096x1024
  unsigned short* Wqkvb  = Xb + 4194304;           // 1024x3072
  unsigned short* Wprojb = Wqkvb + 3145728;        // 1024x1024
  unsigned short* Qb     = Wprojb + 1048576;       // 32x2048x64
  unsigned short* Kb     = Qb + 4194304;
  unsigned short* Vtb    = Kb + 4194304;           // 32x64x2048
  unsigned short* AOb    = Vtb + 4194304;          // 4096x1024

  cast_kernel<<<4096, 256, 0, stream>>>(x, Xb, 1048576);
  cast_kernel<<<3072, 256, 0, stream>>>(Wqkv, Wqkvb, 786432);
  cast_kernel<<<1024, 256, 0, stream>>>(Wproj, Wprojb, 262144);

  gemm_qkv<<<dim3(48, 64), 256, 0, stream>>>(Xb, Wqkvb, bqkv, Qb, Kb, Vtb);
  attn_kernel<<<dim3(32, 32), 256, 0, stream>>>(Qb, Kb, Vtb, AOb);
  gemm_proj<<<dim3(16, 64), 256, 0, stream>>>(AOb, Wprojb, bproj, out);
}

// Round 2
// 243.182 us; speedup vs baseline: 1.8194x; 1.8194x over previous
//
#include <hip/hip_runtime.h>

typedef float floatx4 __attribute__((ext_vector_type(4)));
typedef __bf16 bf16x8 __attribute__((ext_vector_type(8)));

#define MFMA16 __builtin_amdgcn_mfma_f32_16x16x32_bf16

typedef const __attribute__((address_space(1))) void* gas_t;
typedef __attribute__((address_space(3))) void* las_t;
// global -> LDS direct DMA, 16B per lane; LDS dest = wave-uniform base + lane*16
#define GLD16(g, l) __builtin_amdgcn_global_load_lds((gas_t)(g), (las_t)(l), 16, 0, 0)

static __device__ __forceinline__ unsigned short f2bf(float f) {
  union { float f; unsigned int u; } v; v.f = f;
  unsigned int r = v.u + 0x7fffu + ((v.u >> 16) & 1u);
  return (unsigned short)(r >> 16);
}

// ---------------- cast fp32 -> bf16, vectorized x4 ----------------
__global__ void cast_kernel(const float* __restrict__ in,
                            unsigned short* __restrict__ out, int n4) {
  int i = blockIdx.x * blockDim.x + threadIdx.x;
  if (i < n4) {
    float4 v = ((const float4*)in)[i];
    ushort4 o;
    o.x = f2bf(v.x); o.y = f2bf(v.y); o.z = f2bf(v.z); o.w = f2bf(v.w);
    ((ushort4*)out)[i] = o;
  }
}

// ---------------- cast + transpose: in [R][C] fp32 -> out [C][R] bf16 -------
__global__ __launch_bounds__(256) void cast_transpose(
    const float* __restrict__ in, unsigned short* __restrict__ out,
    int R, int C) {
  const int r0 = blockIdx.y * 64, c0 = blockIdx.x * 64;
  const int tid = threadIdx.x;
  __shared__ float tl[64][65];
  const int rr = tid >> 4, cc = (tid & 15) * 4;
#pragma unroll
  for (int i = 0; i < 4; ++i) {
    int row = rr + i * 16;
    float4 v = *(const float4*)(in + (size_t)(r0 + row) * C + c0 + cc);
    tl[row][cc] = v.x; tl[row][cc + 1] = v.y;
    tl[row][cc + 2] = v.z; tl[row][cc + 3] = v.w;
  }
  __syncthreads();
  const int cl = tid >> 2, rbase = (tid & 3) * 16;
  unsigned short o[16];
#pragma unroll
  for (int j = 0; j < 16; ++j) o[j] = f2bf(tl[rbase + j][cl]);
  unsigned short* dst = out + (size_t)(c0 + cl) * R + r0 + rbase;
  *(uint4*)dst = *(uint4*)o;
  *(uint4*)(dst + 8) = *(uint4*)(o + 8);
}

// ---------------- GEMM1: QKV = Xb @ WqkvT^T + bqkv, scatter to Q/K/Vt -------
// A [4096][1024] bf16, Bt [3072][1024] bf16 (pre-transposed weights).
// 128x128 tile, BK=64, global_load_lds staging, XOR-swizzled LDS.
// Q gets the 0.5 attention scale folded in.
__global__ __launch_bounds__(256) void gemm_qkv(
    const unsigned short* __restrict__ A,
    const unsigned short* __restrict__ Bt,
    const float* __restrict__ bias,
    unsigned short* __restrict__ Q,
    unsigned short* __restrict__ Kc,
    unsigned short* __restrict__ Vt) {
  const int K = 1024;
  const int m0 = blockIdx.y * 128, n0 = blockIdx.x * 128;
  const int tid = threadIdx.x, w = tid >> 6, l = tid & 63;
  const int l16 = l & 15, lq = l >> 4;
  const int wm = w >> 1, wn = w & 1;

  __shared__ unsigned short As[128 * 64];
  __shared__ unsigned short Bs[128 * 64];

  floatx4 acc[4][4] = {};

  int sA[4], sB[4];
  unsigned ldso[4];
#pragma unroll
  for (int j = 0; j < 4; ++j) {
    int s = j * 256 + tid;
    int row = s >> 3, blk = (s & 7) ^ (row & 7);
    sA[j] = (m0 + row) * K + blk * 8;
    sB[j] = (n0 + row) * K + blk * 8;
    ldso[j] = (unsigned)(j * 256 + w * 64) * 8;  // ushort index (slot*16B)
  }

  for (int k0 = 0; k0 < K; k0 += 64) {
    __syncthreads();
#pragma unroll
    for (int j = 0; j < 4; ++j) {
      GLD16(A + sA[j] + k0, As + ldso[j]);
      GLD16(Bt + sB[j] + k0, Bs + ldso[j]);
    }
    __syncthreads();
#pragma unroll
    for (int kk = 0; kk < 2; ++kk) {
      bf16x8 af[4], bf[4];
#pragma unroll
      for (int mi = 0; mi < 4; ++mi) {
        int row = wm * 64 + mi * 16 + l16;
        int blk = (kk * 4 + lq) ^ (l16 & 7);
        af[mi] = *(const bf16x8*)(As + row * 64 + blk * 8);
      }
#pragma unroll
      for (int ni = 0; ni < 4; ++ni) {
        int row = wn * 64 + ni * 16 + l16;
        int blk = (kk * 4 + lq) ^ (l16 & 7);
        bf[ni] = *(const bf16x8*)(Bs + row * 64 + blk * 8);
      }
#pragma unroll
      for (int ni = 0; ni < 4; ++ni)
#pragma unroll
        for (int mi = 0; mi < 4; ++mi)
          acc[mi][ni] = MFMA16(af[mi], bf[ni], acc[mi][ni], 0, 0, 0);
    }
  }

  const int which = n0 >> 10;
  float bv[4];
#pragma unroll
  for (int ni = 0; ni < 4; ++ni) bv[ni] = bias[n0 + wn * 64 + ni * 16 + l16];
#pragma unroll
  for (int mi = 0; mi < 4; ++mi) {
#pragma unroll
    for (int ni = 0; ni < 4; ++ni) {
      int col = n0 + wn * 64 + ni * 16 + l16;
      int c1 = col & 1023;
      int h = c1 >> 6, dd = c1 & 63;
#pragma unroll
      for (int r = 0; r < 4; ++r) {
        int row = m0 + wm * 64 + mi * 16 + lq * 4 + r;
        int bb = row >> 11, tt = row & 2047;
        float v = acc[mi][ni][r] + bv[ni];
        size_t bh = (size_t)(bb * 16 + h);
        if (which == 0)      Q [(bh * 2048 + tt) * 64 + dd] = f2bf(v * 0.5f);
        else if (which == 1) Kc[(bh * 2048 + tt) * 64 + dd] = f2bf(v);
        else                 Vt[(bh * 64 + dd) * 2048 + tt] = f2bf(v);
      }
    }
  }
}

// ---------------- attention: no-max softmax, BK=64, dbuf, 1 barrier/iter ----
__global__ __launch_bounds__(256) void attn_kernel(
    const unsigned short* __restrict__ Q,
    const unsigned short* __restrict__ Kc,
    const unsigned short* __restrict__ Vt,
    unsigned short* __restrict__ AO) {
  const int T = 2048;
  const int bh = blockIdx.y, q0 = blockIdx.x * 64;
  const int tid = threadIdx.x, w = tid >> 6, l = tid & 63;
  const int l16 = l & 15, lq = l >> 4;

  __shared__ unsigned short Ks[2][64 * 64];
  __shared__ unsigned short Vs[2][64 * 64];
  __shared__ unsigned short Ps[4][16 * 72];  // per-wave, stride 72 vs conflicts

  // Q fragment (scale already folded in at QKV epilogue)
  const unsigned short* qb = Q + ((size_t)bh * T + q0 + w * 16 + l16) * 64;
  bf16x8 qf0 = *(const bf16x8*)(qb + lq * 8);
  bf16x8 qf1 = *(const bf16x8*)(qb + 32 + lq * 8);

  float l_part[4] = {0.f, 0.f, 0.f, 0.f};
  floatx4 o_acc[4] = {};

  const unsigned short* kbase = Kc + (size_t)bh * T * 64;
  const unsigned short* vbase = Vt + (size_t)bh * 64 * T;
  int kro[2], vro[2];
  unsigned ldso[2];
#pragma unroll
  for (int j = 0; j < 2; ++j) {
    int s = j * 256 + tid;
    int row = s >> 3, blk = (s & 7) ^ (row & 7);
    kro[j] = row * 64 + blk * 8;  // + kt*64
    vro[j] = row * T + blk * 8;   // + kt
    ldso[j] = (unsigned)(j * 256 + w * 64) * 8;
  }

  const int swz0 = (0 + lq) ^ (l16 & 7);   // 16B-block index, k/d chunk 0
  const int swz1 = (4 + lq) ^ (l16 & 7);   // chunk 1

  // prologue stage
#pragma unroll
  for (int j = 0; j < 2; ++j) {
    GLD16(kbase + kro[j], &Ks[0][ldso[j]]);
    GLD16(vbase + vro[j], &Vs[0][ldso[j]]);
  }

  for (int it = 0; it < 32; ++it) {
    __syncthreads();  // buf[it&1] staged (vmcnt drained), prev reads done
    if (it + 1 < 32) {
      int kt = (it + 1) * 64;
      int nb = (it + 1) & 1;
#pragma unroll
      for (int j = 0; j < 2; ++j) {
        GLD16(kbase + kt * 64 + kro[j], &Ks[nb][ldso[j]]);
        GLD16(vbase + kt + vro[j], &Vs[nb][ldso[j]]);
      }
    }
    const unsigned short* kb = Ks[it & 1];
    const unsigned short* vb = Vs[it & 1];

    floatx4 s[4];
#pragma unroll
    for (int ct = 0; ct < 4; ++ct) {
      const unsigned short* kr = kb + (ct * 16 + l16) * 64;
      bf16x8 kf0 = *(const bf16x8*)(kr + swz0 * 8);
      bf16x8 kf1 = *(const bf16x8*)(kr + swz1 * 8);
      floatx4 z = {};
      z = MFMA16(qf0, kf0, z, 0, 0, 0);
      z = MFMA16(qf1, kf1, z, 0, 0, 0);
      s[ct] = z;
    }

    unsigned short* pw = Ps[w];
#pragma unroll
    for (int r = 0; r < 4; ++r) {
      float p0 = __expf(s[0][r]);
      float p1 = __expf(s[1][r]);
      float p2 = __expf(s[2][r]);
      float p3 = __expf(s[3][r]);
      l_part[r] += (p0 + p1) + (p2 + p3);
      int rowo = (lq * 4 + r) * 72 + l16;
      pw[rowo]      = f2bf(p0);
      pw[rowo + 16] = f2bf(p1);
      pw[rowo + 32] = f2bf(p2);
      pw[rowo + 48] = f2bf(p3);
    }
    // intra-wave LDS round-trip: no barrier needed (lgkmcnt ordering)
    bf16x8 pf0 = *(const bf16x8*)(pw + l16 * 72 + lq * 8);
    bf16x8 pf1 = *(const bf16x8*)(pw + l16 * 72 + 32 + lq * 8);
#pragma unroll
    for (int c = 0; c < 4; ++c) {
      const unsigned short* vr = vb + (c * 16 + l16) * 64;
      bf16x8 vf0 = *(const bf16x8*)(vr + swz0 * 8);
      bf16x8 vf1 = *(const bf16x8*)(vr + swz1 * 8);
      o_acc[c] = MFMA16(pf0, vf0, o_acc[c], 0, 0, 0);
      o_acc[c] = MFMA16(pf1, vf1, o_acc[c], 0, 0, 0);
    }
  }

  const int b = bh >> 4, h = bh & 15;
#pragma unroll
  for (int r = 0; r < 4; ++r) {
    float lsum = l_part[r];
#pragma unroll
    for (int xm = 1; xm < 16; xm <<= 1) lsum += __shfl_xor(lsum, xm, 64);
    float inv = 1.0f / lsum;
    int t = q0 + w * 16 + lq * 4 + r;
#pragma unroll
    for (int c = 0; c < 4; ++c) {
      AO[((size_t)b * 2048 + t) * 1024 + h * 64 + c * 16 + l16] =
          f2bf(o_acc[c][r] * inv);
    }
  }
}

// ---------------- GEMM2: out = AO @ WprojT^T + bproj (fp32 out) -------------
__global__ __launch_bounds__(256) void gemm_proj(
    const unsigned short* __restrict__ A,
    const unsigned short* __restrict__ Bt,
    const float* __restrict__ bias,
    float* __restrict__ out) {
  const int K = 1024, N = 1024;
  const int m0 = blockIdx.y * 128, n0 = blockIdx.x * 128;
  const int tid = threadIdx.x, w = tid >> 6, l = tid & 63;
  const int l16 = l & 15, lq = l >> 4;
  const int wm = w >> 1, wn = w & 1;

  __shared__ unsigned short As[128 * 64];
  __shared__ unsigned short Bs[128 * 64];

  floatx4 acc[4][4] = {};

  int sA[4], sB[4];
  unsigned ldso[4];
#pragma unroll
  for (int j = 0; j < 4; ++j) {
    int s = j * 256 + tid;
    int row = s >> 3, blk = (s & 7) ^ (row & 7);
    sA[j] = (m0 + row) * K + blk * 8;
    sB[j] = (n0 + row) * K + blk * 8;
    ldso[j] = (unsigned)(j * 256 + w * 64) * 8;
  }

  for (int k0 = 0; k0 < K; k0 += 64) {
    __syncthreads();
#pragma unroll
    for (int j = 0; j < 4; ++j) {
      GLD16(A + sA[j] + k0, As + ldso[j]);
      GLD16(Bt + sB[j] + k0, Bs + ldso[j]);
    }
    __syncthreads();
#pragma unroll
    for (int kk = 0; kk < 2; ++kk) {
      bf16x8 af[4], bf[4];
#pragma unroll
      for (int mi = 0; mi < 4; ++mi) {
        int row = wm * 64 + mi * 16 + l16;
        int blk = (kk * 4 + lq) ^ (l16 & 7);
        af[mi] = *(const bf16x8*)(As + row * 64 + blk * 8);
      }
#pragma unroll
      for (int ni = 0; ni < 4; ++ni) {
        int row = wn * 64 + ni * 16 + l16;
        int blk = (kk * 4 + lq) ^ (l16 & 7);
        bf[ni] = *(const bf16x8*)(Bs + row * 64 + blk * 8);
      }
#pragma unroll
      for (int ni = 0; ni < 4; ++ni)
#pragma unroll
        for (int mi = 0; mi < 4; ++mi)
          acc[mi][ni] = MFMA16(af[mi], bf[ni], acc[mi][ni], 0, 0, 0);
    }
  }

#pragma unroll
  for (int ni = 0; ni < 4; ++ni) {
    int col = n0 + wn * 64 + ni * 16 + l16;
    float bv = bias[col];
#pragma unroll
    for (int mi = 0; mi < 4; ++mi) {
#pragma unroll
      for (int r = 0; r < 4; ++r) {
        int row = m0 + wm * 64 + mi * 16 + lq * 4 + r;
        out[(size_t)row * N + col] = acc[mi][ni][r] + bv;
      }
    }
  }
}

extern "C" void kernel_launch(void* const* d_in, const int* in_sizes, int n_in,
                              void* d_out, int out_size, void* d_ws,
                              size_t ws_size, hipStream_t stream) {
  const float* x     = (const float*)d_in[0];
  const float* Wqkv  = (const float*)d_in[1];
  const float* bqkv  = (const float*)d_in[2];
  const float* Wproj = (const float*)d_in[3];
  const float* bproj = (const float*)d_in[4];
  float* out = (float*)d_out;

  // workspace layout (bf16 elements), total 48 MiB
  unsigned short* Xb     = (unsigned short*)d_ws;  // 4096x1024
  unsigned short* Wqkvt  = Xb + 4194304;           // 3072x1024 (transposed)
  unsigned short* Wprojt = Wqkvt + 3145728;        // 1024x1024 (transposed)
  unsigned short* Qb     = Wprojt + 1048576;       // 32x2048x64 (pre-scaled)
  unsigned short* Kb     = Qb + 4194304;           // 32x2048x64
  unsigned short* Vtb    = Kb + 4194304;           // 32x64x2048
  unsigned short* AOb    = Vtb + 4194304;          // 4096x1024

  cast_kernel<<<4096, 256, 0, stream>>>(x, Xb, 1048576);
  cast_transpose<<<dim3(48, 16), 256, 0, stream>>>(Wqkv, Wqkvt, 1024, 3072);
  cast_transpose<<<dim3(16, 16), 256, 0, stream>>>(Wproj, Wprojt, 1024, 1024);

  gemm_qkv<<<dim3(24, 32), 256, 0, stream>>>(Xb, Wqkvt, bqkv, Qb, Kb, Vtb);
  attn_kernel<<<dim3(32, 32), 256, 0, stream>>>(Qb, Kb, Vtb, AOb);
  gemm_proj<<<dim3(8, 32), 256, 0, stream>>>(AOb, Wprojt, bproj, out);
}

// Round 3
// 210.298 us; speedup vs baseline: 2.1039x; 1.1564x over previous
//
#include <hip/hip_runtime.h>

typedef float floatx4 __attribute__((ext_vector_type(4)));
typedef __bf16 bf16x8 __attribute__((ext_vector_type(8)));
typedef __bf16 bf16x4 __attribute__((ext_vector_type(4)));

#define MFMA16 __builtin_amdgcn_mfma_f32_16x16x32_bf16

typedef const __attribute__((address_space(1))) void* gas_t;
typedef __attribute__((address_space(3))) void* las_t;
#define GLD16(g, l) __builtin_amdgcn_global_load_lds((gas_t)(g), (las_t)(l), 16, 0, 0)

static __device__ __forceinline__ unsigned short f2bf(float f) {
  union { float f; unsigned int u; } v; v.f = f;
  unsigned int r = v.u + 0x7fffu + ((v.u >> 16) & 1u);
  return (unsigned short)(r >> 16);
}

// ---------------- cast fp32 -> bf16, vectorized x4 ----------------
__global__ void cast_kernel(const float* __restrict__ in,
                            unsigned short* __restrict__ out, int n4) {
  int i = blockIdx.x * blockDim.x + threadIdx.x;
  if (i < n4) {
    float4 v = ((const float4*)in)[i];
    ushort4 o;
    o.x = f2bf(v.x); o.y = f2bf(v.y); o.z = f2bf(v.z); o.w = f2bf(v.w);
    ((ushort4*)out)[i] = o;
  }
}

// ---------------- cast + transpose: in [R][C] fp32 -> out [C][R] bf16 -------
__global__ __launch_bounds__(256) void cast_transpose(
    const float* __restrict__ in, unsigned short* __restrict__ out,
    int R, int C) {
  const int r0 = blockIdx.y * 64, c0 = blockIdx.x * 64;
  const int tid = threadIdx.x;
  __shared__ float tl[64][65];
  const int rr = tid >> 4, cc = (tid & 15) * 4;
#pragma unroll
  for (int i = 0; i < 4; ++i) {
    int row = rr + i * 16;
    float4 v = *(const float4*)(in + (size_t)(r0 + row) * C + c0 + cc);
    tl[row][cc] = v.x; tl[row][cc + 1] = v.y;
    tl[row][cc + 2] = v.z; tl[row][cc + 3] = v.w;
  }
  __syncthreads();
  const int cl = tid >> 2, rbase = (tid & 3) * 16;
  unsigned short o[16];
#pragma unroll
  for (int j = 0; j < 16; ++j) o[j] = f2bf(tl[rbase + j][cl]);
  unsigned short* dst = out + (size_t)(c0 + cl) * R + r0 + rbase;
  *(uint4*)dst = *(uint4*)o;
  *(uint4*)(dst + 8) = *(uint4*)(o + 8);
}

// ---------------- GEMM1: QKV = Xb @ WqkvT^T + bqkv, scatter to Q/K/Vt -------
// Q gets 0.5*log2(e) folded in (attention uses exp2 directly).
__global__ __launch_bounds__(256) void gemm_qkv(
    const unsigned short* __restrict__ A,
    const unsigned short* __restrict__ Bt,
    const float* __restrict__ bias,
    unsigned short* __restrict__ Q,
    unsigned short* __restrict__ Kc,
    unsigned short* __restrict__ Vt) {
  const int K = 1024;
  const int m0 = blockIdx.y * 128, n0 = blockIdx.x * 128;
  const int tid = threadIdx.x, w = tid >> 6, l = tid & 63;
  const int l16 = l & 15, lq = l >> 4;
  const int wm = w >> 1, wn = w & 1;

  __shared__ unsigned short As[128 * 64];
  __shared__ unsigned short Bs[128 * 64];

  floatx4 acc[4][4] = {};

  int sA[4], sB[4];
  unsigned ldso[4];
#pragma unroll
  for (int j = 0; j < 4; ++j) {
    int s = j * 256 + tid;
    int row = s >> 3, blk = (s & 7) ^ (row & 7);
    sA[j] = (m0 + row) * K + blk * 8;
    sB[j] = (n0 + row) * K + blk * 8;
    ldso[j] = (unsigned)(j * 256 + w * 64) * 8;
  }

  for (int k0 = 0; k0 < K; k0 += 64) {
    __syncthreads();
#pragma unroll
    for (int j = 0; j < 4; ++j) {
      GLD16(A + sA[j] + k0, As + ldso[j]);
      GLD16(Bt + sB[j] + k0, Bs + ldso[j]);
    }
    __syncthreads();
#pragma unroll
    for (int kk = 0; kk < 2; ++kk) {
      bf16x8 af[4], bf[4];
#pragma unroll
      for (int mi = 0; mi < 4; ++mi) {
        int row = wm * 64 + mi * 16 + l16;
        int blk = (kk * 4 + lq) ^ (l16 & 7);
        af[mi] = *(const bf16x8*)(As + row * 64 + blk * 8);
      }
#pragma unroll
      for (int ni = 0; ni < 4; ++ni) {
        int row = wn * 64 + ni * 16 + l16;
        int blk = (kk * 4 + lq) ^ (l16 & 7);
        bf[ni] = *(const bf16x8*)(Bs + row * 64 + blk * 8);
      }
#pragma unroll
      for (int ni = 0; ni < 4; ++ni)
#pragma unroll
        for (int mi = 0; mi < 4; ++mi)
          acc[mi][ni] = MFMA16(af[mi], bf[ni], acc[mi][ni], 0, 0, 0);
    }
  }

  const int which = n0 >> 10;
  float bv[4];
#pragma unroll
  for (int ni = 0; ni < 4; ++ni) bv[ni] = bias[n0 + wn * 64 + ni * 16 + l16];
#pragma unroll
  for (int mi = 0; mi < 4; ++mi) {
#pragma unroll
    for (int ni = 0; ni < 4; ++ni) {
      int col = n0 + wn * 64 + ni * 16 + l16;
      int c1 = col & 1023;
      int h = c1 >> 6, dd = c1 & 63;
      int row0 = m0 + wm * 64 + mi * 16 + lq * 4;
      int bb = row0 >> 11, tt0 = row0 & 2047;
      size_t bh = (size_t)(bb * 16 + h);
      if (which == 2) {
        floatx4 vv = acc[mi][ni] + bv[ni];
        bf16x4 ob = __builtin_convertvector(vv, bf16x4);
        *(bf16x4*)(Vt + (bh * 64 + dd) * 2048 + tt0) = ob;
      } else {
#pragma unroll
        for (int r = 0; r < 4; ++r) {
          float v = acc[mi][ni][r] + bv[ni];
          size_t idx = (bh * 2048 + tt0 + r) * 64 + dd;
          if (which == 0) Q[idx] = f2bf(v * 0.7213475204444817f);
          else            Kc[idx] = f2bf(v);
        }
      }
    }
  }
}

// ---------------- attention: S^T scheme, 128 q/block, exp2, packed P --------
__global__ __launch_bounds__(256) void attn_kernel(
    const unsigned short* __restrict__ Q,
    const unsigned short* __restrict__ Kc,
    const unsigned short* __restrict__ Vt,
    unsigned short* __restrict__ AO) {
  const int T = 2048;
  const int bh = blockIdx.y, q0 = blockIdx.x * 128;
  const int tid = threadIdx.x, w = tid >> 6, l = tid & 63;
  const int l16 = l & 15, lq = l >> 4;

  __shared__ unsigned short Ks[2][64 * 64];
  __shared__ unsigned short Vs[2][64 * 64];
  __shared__ unsigned short Ps[4][32 * 72];  // per-wave P^T as [q_local][k]

  // Q fragments: wave owns 32 q (2 subtiles of 16); scale+log2e pre-folded
  bf16x8 qf[2][2];
#pragma unroll
  for (int qs = 0; qs < 2; ++qs) {
    const unsigned short* qb =
        Q + ((size_t)bh * T + q0 + w * 32 + qs * 16 + l16) * 64;
    qf[qs][0] = *(const bf16x8*)(qb + lq * 8);
    qf[qs][1] = *(const bf16x8*)(qb + 32 + lq * 8);
  }

  float l_lane[2] = {0.f, 0.f};
  floatx4 o_acc[4][2] = {};

  const unsigned short* kbase = Kc + (size_t)bh * T * 64;
  const unsigned short* vbase = Vt + (size_t)bh * 64 * T;
  int kro[2], vro[2];
  unsigned ldso[2];
#pragma unroll
  for (int j = 0; j < 2; ++j) {
    int s = j * 256 + tid;
    int row = s >> 3, blk = (s & 7) ^ (row & 7);
    kro[j] = row * 64 + blk * 8;
    vro[j] = row * T + blk * 8;
    ldso[j] = (unsigned)(j * 256 + w * 64) * 8;
  }

  const int swz0 = (0 + lq) ^ (l16 & 7);
  const int swz1 = (4 + lq) ^ (l16 & 7);

#pragma unroll
  for (int j = 0; j < 2; ++j) {
    GLD16(kbase + kro[j], &Ks[0][ldso[j]]);
    GLD16(vbase + vro[j], &Vs[0][ldso[j]]);
  }

  for (int it = 0; it < 32; ++it) {
    __syncthreads();
    if (it + 1 < 32) {
      int kt = (it + 1) * 64;
      int nb = (it + 1) & 1;
#pragma unroll
      for (int j = 0; j < 2; ++j) {
        GLD16(kbase + kt * 64 + kro[j], &Ks[nb][ldso[j]]);
        GLD16(vbase + kt + vro[j], &Vs[nb][ldso[j]]);
      }
    }
    const unsigned short* kb = Ks[it & 1];
    const unsigned short* vb = Vs[it & 1];

    // S^T tiles: D[k=ct*16+lq*4+r][q=w*32+qs*16+l16]
    floatx4 st[2][4];
#pragma unroll
    for (int ct = 0; ct < 4; ++ct) {
      const unsigned short* kr = kb + (ct * 16 + l16) * 64;
      bf16x8 kf0 = *(const bf16x8*)(kr + swz0 * 8);
      bf16x8 kf1 = *(const bf16x8*)(kr + swz1 * 8);
#pragma unroll
      for (int qs = 0; qs < 2; ++qs) {
        floatx4 z = {};
        z = MFMA16(kf0, qf[qs][0], z, 0, 0, 0);
        z = MFMA16(kf1, qf[qs][1], z, 0, 0, 0);
        st[qs][ct] = z;
      }
    }

    // softmax numerators: p = exp2(s); lane's 4 values are consecutive k
    unsigned short* pw = Ps[w];
#pragma unroll
    for (int qs = 0; qs < 2; ++qs) {
#pragma unroll
      for (int ct = 0; ct < 4; ++ct) {
        floatx4 pv;
        pv[0] = __builtin_amdgcn_exp2f(st[qs][ct][0]);
        pv[1] = __builtin_amdgcn_exp2f(st[qs][ct][1]);
        pv[2] = __builtin_amdgcn_exp2f(st[qs][ct][2]);
        pv[3] = __builtin_amdgcn_exp2f(st[qs][ct][3]);
        l_lane[qs] += (pv[0] + pv[1]) + (pv[2] + pv[3]);
        bf16x4 pb = __builtin_convertvector(pv, bf16x4);
        *(bf16x4*)(pw + (qs * 16 + l16) * 72 + ct * 16 + lq * 4) = pb;
      }
    }

    // P^T B-fragments (intra-wave LDS round-trip, lgkmcnt-ordered)
    bf16x8 pf[2][2];
#pragma unroll
    for (int qs = 0; qs < 2; ++qs) {
      const unsigned short* pr = pw + (qs * 16 + l16) * 72;
      pf[qs][0] = *(const bf16x8*)(pr + lq * 8);
      pf[qs][1] = *(const bf16x8*)(pr + 32 + lq * 8);
    }

    // O^T += V^T * P^T : D[d=dt*16+lq*4+r][q]
#pragma unroll
    for (int dt = 0; dt < 4; ++dt) {
      const unsigned short* vr = vb + (dt * 16 + l16) * 64;
      bf16x8 vf0 = *(const bf16x8*)(vr + swz0 * 8);
      bf16x8 vf1 = *(const bf16x8*)(vr + swz1 * 8);
#pragma unroll
      for (int qs = 0; qs < 2; ++qs) {
        o_acc[dt][qs] = MFMA16(vf0, pf[qs][0], o_acc[dt][qs], 0, 0, 0);
        o_acc[dt][qs] = MFMA16(vf1, pf[qs][1], o_acc[dt][qs], 0, 0, 0);
      }
    }
  }

  const int b = bh >> 4, h = bh & 15;
#pragma unroll
  for (int qs = 0; qs < 2; ++qs) {
    float ls = l_lane[qs];
    ls += __shfl_xor(ls, 16, 64);
    ls += __shfl_xor(ls, 32, 64);
    float inv = 1.0f / ls;
    int t = q0 + w * 32 + qs * 16 + l16;
#pragma unroll
    for (int dt = 0; dt < 4; ++dt) {
      floatx4 ov = o_acc[dt][qs] * inv;
      bf16x4 ob = __builtin_convertvector(ov, bf16x4);
      *(bf16x4*)(AO + ((size_t)b * 2048 + t) * 1024 + h * 64 + dt * 16 +
                 lq * 4) = ob;
    }
  }
}

// ---------------- GEMM2: out = AO @ WprojT^T + bproj (fp32 out) -------------
__global__ __launch_bounds__(256) void gemm_proj(
    const unsigned short* __restrict__ A,
    const unsigned short* __restrict__ Bt,
    const float* __restrict__ bias,
    float* __restrict__ out) {
  const int K = 1024, N = 1024;
  const int m0 = blockIdx.y * 128, n0 = blockIdx.x * 128;
  const int tid = threadIdx.x, w = tid >> 6, l = tid & 63;
  const int l16 = l & 15, lq = l >> 4;
  const int wm = w >> 1, wn = w & 1;

  __shared__ unsigned short As[128 * 64];
  __shared__ unsigned short Bs[128 * 64];

  floatx4 acc[4][4] = {};

  int sA[4], sB[4];
  unsigned ldso[4];
#pragma unroll
  for (int j = 0; j < 4; ++j) {
    int s = j * 256 + tid;
    int row = s >> 3, blk = (s & 7) ^ (row & 7);
    sA[j] = (m0 + row) * K + blk * 8;
    sB[j] = (n0 + row) * K + blk * 8;
    ldso[j] = (unsigned)(j * 256 + w * 64) * 8;
  }

  for (int k0 = 0; k0 < K; k0 += 64) {
    __syncthreads();
#pragma unroll
    for (int j = 0; j < 4; ++j) {
      GLD16(A + sA[j] + k0, As + ldso[j]);
      GLD16(Bt + sB[j] + k0, Bs + ldso[j]);
    }
    __syncthreads();
#pragma unroll
    for (int kk = 0; kk < 2; ++kk) {
      bf16x8 af[4], bf[4];
#pragma unroll
      for (int mi = 0; mi < 4; ++mi) {
        int row = wm * 64 + mi * 16 + l16;
        int blk = (kk * 4 + lq) ^ (l16 & 7);
        af[mi] = *(const bf16x8*)(As + row * 64 + blk * 8);
      }
#pragma unroll
      for (int ni = 0; ni < 4; ++ni) {
        int row = wn * 64 + ni * 16 + l16;
        int blk = (kk * 4 + lq) ^ (l16 & 7);
        bf[ni] = *(const bf16x8*)(Bs + row * 64 + blk * 8);
      }
#pragma unroll
      for (int ni = 0; ni < 4; ++ni)
#pragma unroll
        for (int mi = 0; mi < 4; ++mi)
          acc[mi][ni] = MFMA16(af[mi], bf[ni], acc[mi][ni], 0, 0, 0);
    }
  }

#pragma unroll
  for (int ni = 0; ni < 4; ++ni) {
    int col = n0 + wn * 64 + ni * 16 + l16;
    float bv = bias[col];
#pragma unroll
    for (int mi = 0; mi < 4; ++mi) {
#pragma unroll
      for (int r = 0; r < 4; ++r) {
        int row = m0 + wm * 64 + mi * 16 + lq * 4 + r;
        out[(size_t)row * N + col] = acc[mi][ni][r] + bv;
      }
    }
  }
}

extern "C" void kernel_launch(void* const* d_in, const int* in_sizes, int n_in,
                              void* d_out, int out_size, void* d_ws,
                              size_t ws_size, hipStream_t stream) {
  const float* x     = (const float*)d_in[0];
  const float* Wqkv  = (const float*)d_in[1];
  const float* bqkv  = (const float*)d_in[2];
  const float* Wproj = (const float*)d_in[3];
  const float* bproj = (const float*)d_in[4];
  float* out = (float*)d_out;

  unsigned short* Xb     = (unsigned short*)d_ws;  // 4096x1024
  unsigned short* Wqkvt  = Xb + 4194304;           // 3072x1024 (transposed)
  unsigned short* Wprojt = Wqkvt + 3145728;        // 1024x1024 (transposed)
  unsigned short* Qb     = Wprojt + 1048576;       // 32x2048x64 (pre-scaled)
  unsigned short* Kb     = Qb + 4194304;           // 32x2048x64
  unsigned short* Vtb    = Kb + 4194304;           // 32x64x2048
  unsigned short* AOb    = Vtb + 4194304;          // 4096x1024

  cast_kernel<<<4096, 256, 0, stream>>>(x, Xb, 1048576);
  cast_transpose<<<dim3(48, 16), 256, 0, stream>>>(Wqkv, Wqkvt, 1024, 3072);
  cast_transpose<<<dim3(16, 16), 256, 0, stream>>>(Wproj, Wprojt, 1024, 1024);

  gemm_qkv<<<dim3(24, 32), 256, 0, stream>>>(Xb, Wqkvt, bqkv, Qb, Kb, Vtb);
  attn_kernel<<<dim3(16, 32), 256, 0, stream>>>(Qb, Kb, Vtb, AOb);
  gemm_proj<<<dim3(8, 32), 256, 0, stream>>>(AOb, Wprojt, bproj, out);
}

// Round 4
// 199.518 us; speedup vs baseline: 2.2176x; 1.0540x over previous
//
#include <hip/hip_runtime.h>

typedef float floatx4 __attribute__((ext_vector_type(4)));
typedef __bf16 bf16x8 __attribute__((ext_vector_type(8)));
typedef __bf16 bf16x4 __attribute__((ext_vector_type(4)));

#define MFMA16 __builtin_amdgcn_mfma_f32_16x16x32_bf16

typedef const __attribute__((address_space(1))) void* gas_t;
typedef __attribute__((address_space(3))) void* las_t;
#define GLD16(g, l) __builtin_amdgcn_global_load_lds((gas_t)(g), (las_t)(l), 16, 0, 0)

static __device__ __forceinline__ unsigned short f2bf(float f) {
  union { float f; unsigned int u; } v; v.f = f;
  unsigned int r = v.u + 0x7fffu + ((v.u >> 16) & 1u);
  return (unsigned short)(r >> 16);
}

// ---------------- cast fp32 -> bf16, vectorized x4 ----------------
__global__ void cast_kernel(const float* __restrict__ in,
                            unsigned short* __restrict__ out, int n4) {
  int i = blockIdx.x * blockDim.x + threadIdx.x;
  if (i < n4) {
    float4 v = ((const float4*)in)[i];
    ushort4 o;
    o.x = f2bf(v.x); o.y = f2bf(v.y); o.z = f2bf(v.z); o.w = f2bf(v.w);
    ((ushort4*)out)[i] = o;
  }
}

// ---------------- cast + transpose: in [R][C] fp32 -> out [C][R] bf16 -------
__global__ __launch_bounds__(256) void cast_transpose(
    const float* __restrict__ in, unsigned short* __restrict__ out,
    int R, int C) {
  const int r0 = blockIdx.y * 64, c0 = blockIdx.x * 64;
  const int tid = threadIdx.x;
  __shared__ float tl[64][65];
  const int rr = tid >> 4, cc = (tid & 15) * 4;
#pragma unroll
  for (int i = 0; i < 4; ++i) {
    int row = rr + i * 16;
    float4 v = *(const float4*)(in + (size_t)(r0 + row) * C + c0 + cc);
    tl[row][cc] = v.x; tl[row][cc + 1] = v.y;
    tl[row][cc + 2] = v.z; tl[row][cc + 3] = v.w;
  }
  __syncthreads();
  const int cl = tid >> 2, rbase = (tid & 3) * 16;
  unsigned short o[16];
#pragma unroll
  for (int j = 0; j < 16; ++j) o[j] = f2bf(tl[rbase + j][cl]);
  unsigned short* dst = out + (size_t)(c0 + cl) * R + r0 + rbase;
  *(uint4*)dst = *(uint4*)o;
  *(uint4*)(dst + 8) = *(uint4*)(o + 8);
}

// ---------------- GEMM1: QKV = Xb @ WqkvT^T + bqkv, scatter -----------------
// Qt[bh][d][t] (packed, 0.5*log2e folded), Kc[bh][t][d], Vt[bh][d][t].
__global__ __launch_bounds__(256) void gemm_qkv(
    const unsigned short* __restrict__ A,
    const unsigned short* __restrict__ Bt,
    const float* __restrict__ bias,
    unsigned short* __restrict__ Qt,
    unsigned short* __restrict__ Kc,
    unsigned short* __restrict__ Vt) {
  const int K = 1024;
  const int m0 = blockIdx.y * 128, n0 = blockIdx.x * 128;
  const int tid = threadIdx.x, w = tid >> 6, l = tid & 63;
  const int l16 = l & 15, lq = l >> 4;
  const int wm = w >> 1, wn = w & 1;

  __shared__ unsigned short As[128 * 64];
  __shared__ unsigned short Bs[128 * 64];

  floatx4 acc[4][4] = {};

  int sA[4], sB[4];
  unsigned ldso[4];
#pragma unroll
  for (int j = 0; j < 4; ++j) {
    int s = j * 256 + tid;
    int row = s >> 3, blk = (s & 7) ^ (row & 7);
    sA[j] = (m0 + row) * K + blk * 8;
    sB[j] = (n0 + row) * K + blk * 8;
    ldso[j] = (unsigned)(j * 256 + w * 64) * 8;
  }

  for (int k0 = 0; k0 < K; k0 += 64) {
    __syncthreads();
#pragma unroll
    for (int j = 0; j < 4; ++j) {
      GLD16(A + sA[j] + k0, As + ldso[j]);
      GLD16(Bt + sB[j] + k0, Bs + ldso[j]);
    }
    __syncthreads();
#pragma unroll
    for (int kk = 0; kk < 2; ++kk) {
      bf16x8 af[4], bf[4];
#pragma unroll
      for (int mi = 0; mi < 4; ++mi) {
        int row = wm * 64 + mi * 16 + l16;
        int blk = (kk * 4 + lq) ^ (l16 & 7);
        af[mi] = *(const bf16x8*)(As + row * 64 + blk * 8);
      }
#pragma unroll
      for (int ni = 0; ni < 4; ++ni) {
        int row = wn * 64 + ni * 16 + l16;
        int blk = (kk * 4 + lq) ^ (l16 & 7);
        bf[ni] = *(const bf16x8*)(Bs + row * 64 + blk * 8);
      }
#pragma unroll
      for (int ni = 0; ni < 4; ++ni)
#pragma unroll
        for (int mi = 0; mi < 4; ++mi)
          acc[mi][ni] = MFMA16(af[mi], bf[ni], acc[mi][ni], 0, 0, 0);
    }
  }

  const int which = n0 >> 10;
  float bv[4];
#pragma unroll
  for (int ni = 0; ni < 4; ++ni) bv[ni] = bias[n0 + wn * 64 + ni * 16 + l16];
#pragma unroll
  for (int mi = 0; mi < 4; ++mi) {
#pragma unroll
    for (int ni = 0; ni < 4; ++ni) {
      int col = n0 + wn * 64 + ni * 16 + l16;
      int c1 = col & 1023;
      int h = c1 >> 6, dd = c1 & 63;
      int row0 = m0 + wm * 64 + mi * 16 + lq * 4;
      int bb = row0 >> 11, tt0 = row0 & 2047;
      size_t bh = (size_t)(bb * 16 + h);
      if (which == 2) {
        floatx4 vv = acc[mi][ni] + bv[ni];
        *(bf16x4*)(Vt + (bh * 64 + dd) * 2048 + tt0) =
            __builtin_convertvector(vv, bf16x4);
      } else if (which == 0) {
        floatx4 vv = (acc[mi][ni] + bv[ni]) * 0.7213475204444817f;
        *(bf16x4*)(Qt + (bh * 64 + dd) * 2048 + tt0) =
            __builtin_convertvector(vv, bf16x4);
      } else {
#pragma unroll
        for (int r = 0; r < 4; ++r)
          Kc[(bh * 2048 + tt0 + r) * 64 + dd] = f2bf(acc[mi][ni][r] + bv[ni]);
      }
    }
  }
}

// ---------------- attention: 8 waves, 256 q/block, swizzled Ps --------------
__global__ __launch_bounds__(512) void attn_kernel(
    const unsigned short* __restrict__ Qt,
    const unsigned short* __restrict__ Kc,
    const unsigned short* __restrict__ Vt,
    unsigned short* __restrict__ AO) {
  const int T = 2048;
  const int bh = blockIdx.y, q0 = blockIdx.x * 256;
  const int tid = threadIdx.x, w = tid >> 6, l = tid & 63;
  const int l16 = l & 15, lq = l >> 4;

  __shared__ unsigned short Ks[2][64 * 64];   // 16 KB
  __shared__ unsigned short Vs[2][64 * 64];   // 16 KB
  __shared__ unsigned short Ps[8][32 * 64];   // 32 KB, XOR-swizzled 16B blocks

  // Q fragments from Qt[bh][d][t] (scale+log2e pre-folded): 32 scalar loads
  bf16x8 qf[2][2];
  {
    const unsigned short* qtb = Qt + (size_t)bh * 64 * 2048 + q0 + w * 32;
#pragma unroll
    for (int qs = 0; qs < 2; ++qs) {
      int t = qs * 16 + l16;
#pragma unroll
      for (int c2 = 0; c2 < 2; ++c2)
#pragma unroll
        for (int j = 0; j < 8; ++j) {
          int d = c2 * 32 + lq * 8 + j;
          qf[qs][c2][j] = ((const __bf16*)qtb)[(size_t)d * 2048 + t];
        }
    }
  }

  float l_lane[2] = {0.f, 0.f};
  floatx4 o_acc[4][2] = {};

  const unsigned short* kbase = Kc + (size_t)bh * T * 64;
  const unsigned short* vbase = Vt + (size_t)bh * 64 * T;
  const int srow = tid >> 3, sblk = (tid & 7) ^ (srow & 7);
  const int kro = srow * 64 + sblk * 8;
  const int vro = srow * T + sblk * 8;
  const unsigned ldso = (unsigned)(w * 64) * 8;

  const int swz0 = (0 + lq) ^ (l16 & 7);
  const int swz1 = (4 + lq) ^ (l16 & 7);

  GLD16(kbase + kro, &Ks[0][ldso]);
  GLD16(vbase + vro, &Vs[0][ldso]);

  for (int it = 0; it < 32; ++it) {
    __syncthreads();
    if (it + 1 < 32) {
      int kt = (it + 1) * 64, nb = (it + 1) & 1;
      GLD16(kbase + kt * 64 + kro, &Ks[nb][ldso]);
      GLD16(vbase + kt + vro, &Vs[nb][ldso]);
    }
    const unsigned short* kb = Ks[it & 1];
    const unsigned short* vb = Vs[it & 1];

    // S^T: D[k_t = ct*16+lq*4+r][q = w*32+qs*16+l16]
    floatx4 st[2][4];
#pragma unroll
    for (int ct = 0; ct < 4; ++ct) {
      const unsigned short* kr = kb + (ct * 16 + l16) * 64;
      bf16x8 kf0 = *(const bf16x8*)(kr + swz0 * 8);
      bf16x8 kf1 = *(const bf16x8*)(kr + swz1 * 8);
#pragma unroll
      for (int qs = 0; qs < 2; ++qs) {
        floatx4 z = {};
        z = MFMA16(kf0, qf[qs][0], z, 0, 0, 0);
        z = MFMA16(kf1, qf[qs][1], z, 0, 0, 0);
        st[qs][ct] = z;
      }
    }

    unsigned short* pw = Ps[w];
#pragma unroll
    for (int qs = 0; qs < 2; ++qs) {
#pragma unroll
      for (int ct = 0; ct < 4; ++ct) {
        floatx4 pv;
        pv[0] = __builtin_amdgcn_exp2f(st[qs][ct][0]);
        pv[1] = __builtin_amdgcn_exp2f(st[qs][ct][1]);
        pv[2] = __builtin_amdgcn_exp2f(st[qs][ct][2]);
        pv[3] = __builtin_amdgcn_exp2f(st[qs][ct][3]);
        l_lane[qs] += (pv[0] + pv[1]) + (pv[2] + pv[3]);
        bf16x4 pb = __builtin_convertvector(pv, bf16x4);
        int blk16 = (ct * 2 + (lq >> 1)) ^ (l16 & 7);
        *(bf16x4*)(pw + (qs * 16 + l16) * 64 + blk16 * 8 + (lq & 1) * 4) = pb;
      }
    }

    // P^T B-fragments (intra-wave LDS round-trip, swizzled reads)
    bf16x8 pf[2][2];
#pragma unroll
    for (int qs = 0; qs < 2; ++qs)
#pragma unroll
      for (int c2 = 0; c2 < 2; ++c2) {
        int blkr = (c2 * 4 + lq) ^ (l16 & 7);
        pf[qs][c2] = *(const bf16x8*)(pw + (qs * 16 + l16) * 64 + blkr * 8);
      }

    // O^T += V^T * P^T
#pragma unroll
    for (int dt = 0; dt < 4; ++dt) {
      const unsigned short* vr = vb + (dt * 16 + l16) * 64;
      bf16x8 vf0 = *(const bf16x8*)(vr + swz0 * 8);
      bf16x8 vf1 = *(const bf16x8*)(vr + swz1 * 8);
#pragma unroll
      for (int qs = 0; qs < 2; ++qs) {
        o_acc[dt][qs] = MFMA16(vf0, pf[qs][0], o_acc[dt][qs], 0, 0, 0);
        o_acc[dt][qs] = MFMA16(vf1, pf[qs][1], o_acc[dt][qs], 0, 0, 0);
      }
    }
  }

  const int b = bh >> 4, h = bh & 15;
#pragma unroll
  for (int qs = 0; qs < 2; ++qs) {
    float ls = l_lane[qs];
    ls += __shfl_xor(ls, 16, 64);
    ls += __shfl_xor(ls, 32, 64);
    float inv = 1.0f / ls;
    int t = q0 + w * 32 + qs * 16 + l16;
#pragma unroll
    for (int dt = 0; dt < 4; ++dt) {
      floatx4 ov = o_acc[dt][qs] * inv;
      bf16x4 ob = __builtin_convertvector(ov, bf16x4);
      *(bf16x4*)(AO + ((size_t)b * 2048 + t) * 1024 + h * 64 + dt * 16 +
                 lq * 4) = ob;
    }
  }
}

// ---------------- GEMM2: out = AO @ WprojT^T + bproj, 128x64 tiles ----------
__global__ __launch_bounds__(256) void gemm_proj(
    const unsigned short* __restrict__ A,
    const unsigned short* __restrict__ Bt,
    const float* __restrict__ bias,
    float* __restrict__ out) {
  const int K = 1024, N = 1024;
  const int m0 = blockIdx.y * 128, n0 = blockIdx.x * 64;
  const int tid = threadIdx.x, w = tid >> 6, l = tid & 63;
  const int l16 = l & 15, lq = l >> 4;

  __shared__ unsigned short As[128 * 64];
  __shared__ unsigned short Bs[64 * 64];

  floatx4 acc[2][4] = {};

  int sA[4], sB[2];
  unsigned ldsoA[4], ldsoB[2];
#pragma unroll
  for (int j = 0; j < 4; ++j) {
    int s = j * 256 + tid;
    int row = s >> 3, blk = (s & 7) ^ (row & 7);
    sA[j] = (m0 + row) * K + blk * 8;
    ldsoA[j] = (unsigned)(j * 256 + w * 64) * 8;
  }
#pragma unroll
  for (int j = 0; j < 2; ++j) {
    int s = j * 256 + tid;
    int row = s >> 3, blk = (s & 7) ^ (row & 7);
    sB[j] = (n0 + row) * K + blk * 8;
    ldsoB[j] = (unsigned)(j * 256 + w * 64) * 8;
  }

  for (int k0 = 0; k0 < K; k0 += 64) {
    __syncthreads();
#pragma unroll
    for (int j = 0; j < 4; ++j) GLD16(A + sA[j] + k0, As + ldsoA[j]);
#pragma unroll
    for (int j = 0; j < 2; ++j) GLD16(Bt + sB[j] + k0, Bs + ldsoB[j]);
    __syncthreads();
#pragma unroll
    for (int kk = 0; kk < 2; ++kk) {
      bf16x8 af[2], bf[4];
#pragma unroll
      for (int mi = 0; mi < 2; ++mi) {
        int row = w * 32 + mi * 16 + l16;
        int blk = (kk * 4 + lq) ^ (l16 & 7);
        af[mi] = *(const bf16x8*)(As + row * 64 + blk * 8);
      }
#pragma unroll
      for (int ni = 0; ni < 4; ++ni) {
        int row = ni * 16 + l16;
        int blk = (kk * 4 + lq) ^ (l16 & 7);
        bf[ni] = *(const bf16x8*)(Bs + row * 64 + blk * 8);
      }
#pragma unroll
      for (int ni = 0; ni < 4; ++ni)
#pragma unroll
        for (int mi = 0; mi < 2; ++mi)
          acc[mi][ni] = MFMA16(af[mi], bf[ni], acc[mi][ni], 0, 0, 0);
    }
  }

#pragma unroll
  for (int ni = 0; ni < 4; ++ni) {
    int col = n0 + ni * 16 + l16;
    float bv = bias[col];
#pragma unroll
    for (int mi = 0; mi < 2; ++mi) {
#pragma unroll
      for (int r = 0; r < 4; ++r) {
        int row = m0 + w * 32 + mi * 16 + lq * 4 + r;
        out[(size_t)row * N + col] = acc[mi][ni][r] + bv;
      }
    }
  }
}

extern "C" void kernel_launch(void* const* d_in, const int* in_sizes, int n_in,
                              void* d_out, int out_size, void* d_ws,
                              size_t ws_size, hipStream_t stream) {
  const float* x     = (const float*)d_in[0];
  const float* Wqkv  = (const float*)d_in[1];
  const float* bqkv  = (const float*)d_in[2];
  const float* Wproj = (const float*)d_in[3];
  const float* bproj = (const float*)d_in[4];
  float* out = (float*)d_out;

  unsigned short* Xb     = (unsigned short*)d_ws;  // 4096x1024
  unsigned short* Wqkvt  = Xb + 4194304;           // 3072x1024 (transposed)
  unsigned short* Wprojt = Wqkvt + 3145728;        // 1024x1024 (transposed)
  unsigned short* Qtb    = Wprojt + 1048576;       // 32x64x2048 (pre-scaled)
  unsigned short* Kb     = Qtb + 4194304;          // 32x2048x64
  unsigned short* Vtb    = Kb + 4194304;           // 32x64x2048
  unsigned short* AOb    = Vtb + 4194304;          // 4096x1024

  cast_kernel<<<4096, 256, 0, stream>>>(x, Xb, 1048576);
  cast_transpose<<<dim3(48, 16), 256, 0, stream>>>(Wqkv, Wqkvt, 1024, 3072);
  cast_transpose<<<dim3(16, 16), 256, 0, stream>>>(Wproj, Wprojt, 1024, 1024);

  gemm_qkv<<<dim3(24, 32), 256, 0, stream>>>(Xb, Wqkvt, bqkv, Qtb, Kb, Vtb);
  attn_kernel<<<dim3(8, 32), 512, 0, stream>>>(Qtb, Kb, Vtb, AOb);
  gemm_proj<<<dim3(16, 32), 256, 0, stream>>>(AOb, Wprojt, bproj, out);
}